// Round 2
// baseline (551.315 us; speedup 1.0000x reference)
//
#include <hip/hip_runtime.h>
#include <cstdint>
#include <math.h>

// ---------------------------------------------------------------------------
// ParallelAttention (GPT-NeoX style), MI355X gfx950.
//   SEQ=2048 BATCH=2 HID=2048 NH=16 HD=128, causal mask, RoPE full head dim.
// INTERFACE (established R0-R7): fp32 inputs, fp32 output, inputs resolved by
//   element count (w_dense = LAST 4194304 match; mask unused).
// R9: GEMMs on m97 structure (bf16 pre-convert + global_load_lds w16).
// R10: attn rebuilt for latency hiding (was MfmaUtil 6.9%, Occ 12.5%, 206us):
//   - 512-thread / 8-wave blocks, 16 q-rows per wave, same 128-row Q tile
//     -> 16 waves/CU (2x latency hiding at same LDS footprint).
//   - pair-balanced (bh,qt) remap: block L<256 gets qt=15-(L&7), L>=256 gets
//     qt=(L-256)&7 -> under round-robin dispatch each CU hosts one long +
//     one complementary short block (per-CU tile count ~const 34).
//   - T14 prefetch: ping-pong K/V register sets; next tile's global loads
//     issued before compute, consumed a full tile later.
//   - mid-barrier removed (P tile is wave-private; same-wave LDS ops are
//     processed in order) -> 2 barriers/tile.
//   - exp2-domain softmax (scale*log2e folded; mask = -10000*log2e) and
//     s_setprio(1) around MFMA clusters (m191: +4-7% attn).
//   - P tile [16][64] bf16 XOR-swizzled (elem c ^= (row&7)<<3): 2-way max
//     banks on b16 write and b128 read; LDS 52224 B total.
// MFMA 16x16x32 bf16: A/B row=lane&15, k=(lane>>4)*8+j; C/D col=lane&15,
//   row=(lane>>4)*4+reg (verified m89/m91).
// global_load_lds: LDS dest is wave-uniform base + lane*16B (m104/m108) --
//   LDS must be LINEAR (stride 64), source address is per-lane.
// ---------------------------------------------------------------------------

typedef unsigned short u16;
typedef __bf16 bf16x8 __attribute__((ext_vector_type(8)));
typedef float floatx4 __attribute__((ext_vector_type(4)));

#define SEQ 2048
#define BATCH 2
#define HID 2048
#define NH 16
#define HD 128
#define LDA 72    // padded row stride (attn Vs, qkv_v Bs)
#define LDK 136   // padded row stride for 128-wide K tile in attn

__device__ __forceinline__ u16 f2bf(float f) {
  union { float f; uint32_t u; } v; v.f = f;
  uint32_t u = v.u;
  return (u16)((u + 0x7FFFu + ((u >> 16) & 1u)) >> 16);
}

// pack 8 fp32 -> 8 bf16 (RNE) and store 16B
__device__ __forceinline__ void st8_bf16(u16* dst, const float* s) {
  uint32_t pk[4];
#pragma unroll
  for (int j = 0; j < 4; j++)
    pk[j] = (uint32_t)f2bf(s[2 * j]) | ((uint32_t)f2bf(s[2 * j + 1]) << 16);
  *(uint4*)dst = make_uint4(pk[0], pk[1], pk[2], pk[3]);
}

// async global->LDS, 16B per lane; lds base must be wave-uniform
__device__ __forceinline__ void gl16(const u16* g, u16* l) {
  __builtin_amdgcn_global_load_lds(
      (const __attribute__((address_space(1))) void*)g,
      (__attribute__((address_space(3))) void*)l, 16, 0, 0);
}

// ---------------- input conversion: w_qkv K/Q tiles + hidden -> bf16 --------
// wb tile order: [K head 0..15][Q head 0..15]; src tile for K h = 3h+1, Q h = 3h.
__global__ __launch_bounds__(256) void cvt_inputs(
    const float* __restrict__ W, const float* __restrict__ Hid,
    u16* __restrict__ wb, u16* __restrict__ Ah) {
  const int blk = blockIdx.x;
  const int c0 = threadIdx.x * 8;
  const float* src;
  u16* dst;
  if (blk < 4096) {
    int dt = blk >> 7, r = blk & 127;
    int srow = (dt < 16) ? ((dt * 3 + 1) * 128 + r) : (((dt - 16) * 3) * 128 + r);
    src = W + (size_t)srow * HID;
    dst = wb + (size_t)blk * HID;
  } else {
    int r = blk - 4096;
    src = Hid + (size_t)r * HID;
    dst = Ah + (size_t)r * HID;
  }
  float t[8];
  *(floatx4*)&t[0] = *(const floatx4*)(src + c0);
  *(floatx4*)&t[4] = *(const floatx4*)(src + c0 + 4);
  st8_bf16(dst + c0, t);
}

// ---------------- w_dense fp32 -> bf16 --------------------------------------
__global__ __launch_bounds__(256) void cvt_wd(const float* __restrict__ W,
                                              u16* __restrict__ wd) {
  const int r = blockIdx.x;
  const int c0 = threadIdx.x * 8;
  float t[8];
  const float* src = W + (size_t)r * HID;
  *(floatx4*)&t[0] = *(const floatx4*)(src + c0);
  *(floatx4*)&t[4] = *(const floatx4*)(src + c0 + 4);
  st8_bf16(wd + (size_t)r * HID + c0, t);
}

// ---------------- QK projection: bf16 @ bf16, gload_lds both operands -------
__global__ __launch_bounds__(256, 2) void qkv_qk(
    const u16* __restrict__ Ah, const u16* __restrict__ wb,
    const float* __restrict__ bias, u16* __restrict__ Qw,
    u16* __restrict__ Kw) {
  __shared__ __align__(16) u16 As[128 * 64];
  __shared__ __align__(16) u16 Bs[128 * 64];
  const int tid = threadIdx.x;
  const int wv = tid >> 6, lane = tid & 63;
  const int quad = lane >> 4, l16 = lane & 15;
  const int wt = blockIdx.x;  // 0..15 = K head wt, 16..31 = Q head wt-16
  const int bm = blockIdx.y;
  const int rowA0 = bm * 128;
  const int wm = (wv >> 1) * 64;
  const int wn = (wv & 1) * 32;
  const int ntoff[4] = {wn, wn + 16, wn + 64, wn + 80};

  const int lrow = wv * 32 + (lane >> 3);
  const int lcol = (lane & 7) * 8;
  const u16* Ag = Ah + (size_t)(rowA0 + lrow) * HID + lcol;
  const u16* Bg = wb + ((size_t)wt * 128 + lrow) * HID + lcol;
  u16* Al = &As[(wv * 32) * 64];  // wave-uniform
  u16* Bl = &Bs[(wv * 32) * 64];

  floatx4 acc[4][4];
#pragma unroll
  for (int i = 0; i < 4; i++)
#pragma unroll
    for (int j = 0; j < 4; j++) acc[i][j] = (floatx4){0.f, 0.f, 0.f, 0.f};

  for (int kb = 0; kb < HID; kb += 64) {
#pragma unroll
    for (int j = 0; j < 4; j++) {
      gl16(Ag + (size_t)j * 8 * HID + kb, Al + j * 8 * 64);
      gl16(Bg + (size_t)j * 8 * HID + kb, Bl + j * 8 * 64);
    }
    __syncthreads();  // drains vmcnt(0): LDS tiles ready
#pragma unroll
    for (int ks = 0; ks < 64; ks += 32) {
      bf16x8 af[4], bfr[4];
#pragma unroll
      for (int mi = 0; mi < 4; mi++)
        af[mi] = *(const bf16x8*)&As[(wm + mi * 16 + l16) * 64 + ks + quad * 8];
#pragma unroll
      for (int ni = 0; ni < 4; ni++)
        bfr[ni] = *(const bf16x8*)&Bs[(ntoff[ni] + l16) * 64 + ks + quad * 8];
#pragma unroll
      for (int mi = 0; mi < 4; mi++)
#pragma unroll
        for (int ni = 0; ni < 4; ni++)
          acc[mi][ni] = __builtin_amdgcn_mfma_f32_16x16x32_bf16(
              af[mi], bfr[ni], acc[mi][ni], 0, 0, 0);
    }
    __syncthreads();  // all waves done reading before next gload_lds overwrite
  }

  // epilogue: bias + RoPE (inline cos/sin)
  const int seg = (wt < 16) ? 1 : 0;  // 1=K, 0=Q
  const int head = wt & 15;
  u16* dst = seg ? Kw : Qw;
  float bv[4];
#pragma unroll
  for (int ni = 0; ni < 4; ni++)
    bv[ni] = bias[(head * 3 + seg) * 128 + ntoff[ni] + l16];
  const float RC = 0.20762050593045951f;  // log2(10000)/64
  const float f0 = exp2f(-(float)(wn + l16) * RC);
  const float f1 = exp2f(-(float)(wn + 16 + l16) * RC);

#pragma unroll
  for (int mi = 0; mi < 4; mi++) {
#pragma unroll
    for (int reg = 0; reg < 4; reg++) {
      int r = rowA0 + wm + mi * 16 + quad * 4 + reg;
      int s = r >> 1, b = r & 1;
      size_t base = ((size_t)(b * NH + head) * SEQ + s) * HD;
      float sv, cv;
      sincosf((float)s * f0, &sv, &cv);
      {
        float lo = acc[mi][0][reg] + bv[0];
        float hi = acc[mi][2][reg] + bv[2];
        dst[base + wn + l16] = f2bf(lo * cv - hi * sv);
        dst[base + wn + l16 + 64] = f2bf(hi * cv + lo * sv);
      }
      sincosf((float)s * f1, &sv, &cv);
      {
        float lo = acc[mi][1][reg] + bv[1];
        float hi = acc[mi][3][reg] + bv[3];
        dst[base + wn + 16 + l16] = f2bf(lo * cv - hi * sv);
        dst[base + wn + 16 + l16 + 64] = f2bf(hi * cv + lo * sv);
      }
    }
  }
}

// ---------------- V projection: A via gload_lds, W fp32 reg-staged ----------
__global__ __launch_bounds__(256, 2) void qkv_v(
    const u16* __restrict__ Ah, const float* __restrict__ W,
    const float* __restrict__ bias, u16* __restrict__ Vt) {
  __shared__ __align__(16) u16 As[128 * 64];
  __shared__ __align__(16) u16 Bs[128 * LDA];
  const int tid = threadIdx.x;
  const int wv = tid >> 6, lane = tid & 63;
  const int quad = lane >> 4, l16 = lane & 15;
  const int head = blockIdx.x;  // 0..15
  const int bm = blockIdx.y;
  const int rowA0 = bm * 128;
  const int rowB0 = (head * 3 + 2) * 128;  // V rows of original w_qkv
  const int wm = (wv >> 1) * 64;
  const int wn = (wv & 1) * 32;
  const int ntoff[4] = {wn, wn + 16, wn + 64, wn + 80};

  const int lrow = wv * 32 + (lane >> 3);
  const int lcol = (lane & 7) * 8;
  const u16* Ag = Ah + (size_t)(rowA0 + lrow) * HID + lcol;
  u16* Al = &As[(wv * 32) * 64];

  floatx4 acc[4][4];
#pragma unroll
  for (int i = 0; i < 4; i++)
#pragma unroll
    for (int j = 0; j < 4; j++) acc[i][j] = (floatx4){0.f, 0.f, 0.f, 0.f};

  for (int kb = 0; kb < HID; kb += 64) {
    float fb[4][8];
#pragma unroll
    for (int i = 0; i < 4; i++) {
      int c = i * 256 + tid;
      int row = c >> 3, k8 = (c & 7) * 8;
      const float* sb = &W[(size_t)(rowB0 + row) * HID + kb + k8];
      *(floatx4*)&fb[i][0] = *(const floatx4*)sb;
      *(floatx4*)&fb[i][4] = *(const floatx4*)(sb + 4);
    }
    __syncthreads();  // prev iteration's MFMA reads done
#pragma unroll
    for (int j = 0; j < 4; j++)
      gl16(Ag + (size_t)j * 8 * HID + kb, Al + j * 8 * 64);
#pragma unroll
    for (int i = 0; i < 4; i++) {
      int c = i * 256 + tid;
      int row = c >> 3, k8 = (c & 7) * 8;
      st8_bf16(&Bs[row * LDA + k8], fb[i]);
    }
    __syncthreads();  // drains vmcnt(0)+lgkmcnt: As,Bs ready
#pragma unroll
    for (int ks = 0; ks < 64; ks += 32) {
      bf16x8 af[4], bfr[4];
#pragma unroll
      for (int mi = 0; mi < 4; mi++)
        af[mi] = *(const bf16x8*)&As[(wm + mi * 16 + l16) * 64 + ks + quad * 8];
#pragma unroll
      for (int ni = 0; ni < 4; ni++)
        bfr[ni] = *(const bf16x8*)&Bs[(ntoff[ni] + l16) * LDA + ks + quad * 8];
#pragma unroll
      for (int mi = 0; mi < 4; mi++)
#pragma unroll
        for (int ni = 0; ni < 4; ni++)
          acc[mi][ni] = __builtin_amdgcn_mfma_f32_16x16x32_bf16(
              af[mi], bfr[ni], acc[mi][ni], 0, 0, 0);
    }
  }
  __syncthreads();

  float bv[4];
#pragma unroll
  for (int ni = 0; ni < 4; ni++)
    bv[ni] = bias[(head * 3 + 2) * 128 + ntoff[ni] + l16];
#pragma unroll
  for (int mi = 0; mi < 4; mi++) {
#pragma unroll
    for (int ni = 0; ni < 4; ni++) {
      int d = ntoff[ni] + l16;
#pragma unroll
      for (int reg = 0; reg < 4; reg++) {
        int r = rowA0 + wm + mi * 16 + quad * 4 + reg;
        int s = r >> 1, b = r & 1;
        Vt[((size_t)(b * NH + head) * HD + d) * SEQ + s] =
            f2bf(acc[mi][ni][reg] + bv[ni]);
      }
    }
  }
}

// ---------------- flash attention: 512 thr / 8 waves, 16 q-rows per wave ----
__global__ __launch_bounds__(512, 4) void attn(
    const u16* __restrict__ Qw, const u16* __restrict__ Kw,
    const u16* __restrict__ Vt, u16* __restrict__ ctx) {
  __shared__ __align__(16) u16 Ks[64 * LDK];      // 17408 B
  __shared__ __align__(16) u16 Vs[128 * LDA];     // 18432 B
  __shared__ __align__(16) u16 Pl[8 * 16 * 64];   // 16384 B, XOR-swizzled

  const int tid = threadIdx.x;  // 0..511
  const int wv = tid >> 6, lane = tid & 63;
  const int quad = lane >> 4, l16 = lane & 15;

  // pair-balanced (bh, qt) map: L and L+256 (same CU under round-robin)
  // get complementary qt -> per-CU tile count ~ constant.
  const int L = blockIdx.x;
  int bh, qt;
  if (L < 256) { bh = L >> 3; qt = 15 - (L & 7); }
  else         { bh = (L - 256) >> 3; qt = (L - 256) & 7; }
  const int b = bh >> 4, h = bh & 15;
  const int sw = qt * 128 + wv * 16;  // this wave's 16 q-rows
  const size_t bhoff = (size_t)bh * SEQ * HD;
  const int pw = wv * 1024;  // wave-private P slice (elements)

  bf16x8 qf[4];
#pragma unroll
  for (int kc = 0; kc < 4; kc++)
    qf[kc] = *(const bf16x8*)&Qw[bhoff + (size_t)(sw + l16) * HD + kc * 32 +
                                 quad * 8];

  floatx4 o[8];
#pragma unroll
  for (int ni = 0; ni < 8; ni++) o[ni] = (floatx4){0.f, 0.f, 0.f, 0.f};
  float mst[4], lst[4];
#pragma unroll
  for (int r = 0; r < 4; r++) { mst[r] = -1e30f; lst[r] = 0.f; }

  const int nt = qt * 2 + 2;
  // log2-domain softmax: scores*(1/sqrt(128)*log2 e), mask = -10000*log2 e
  const float SCL2 = 0.088388347648318447f * 1.442695040888963f;
  const float MSK2 = -10000.0f * 1.442695040888963f;

  // prefetch reg sets (ping-pong): even t stores A/loads B, odd stores B/loads A
  bf16x8 tkA[2], tvA[2], tkB[2], tvB[2];
#pragma unroll
  for (int i = 0; i < 2; i++) {
    int c = i * 512 + tid;
    tkA[i] = *(const bf16x8*)&Kw[bhoff + (size_t)(c >> 4) * HD + (c & 15) * 8];
    tvA[i] = *(const bf16x8*)&Vt[bhoff + (size_t)(c >> 3) * SEQ + (c & 7) * 8];
  }

  for (int t = 0; t < nt; t++) {
    __syncthreads();  // prior tile's LDS reads complete
    if (t & 1) {
#pragma unroll
      for (int i = 0; i < 2; i++) {
        int c = i * 512 + tid;
        *(bf16x8*)&Ks[(c >> 4) * LDK + (c & 15) * 8] = tkB[i];
        *(bf16x8*)&Vs[(c >> 3) * LDA + (c & 7) * 8] = tvB[i];
      }
      if (t + 1 < nt) {
#pragma unroll
        for (int i = 0; i < 2; i++) {
          int c = i * 512 + tid;
          tkA[i] = *(const bf16x8*)&Kw[bhoff +
                                       (size_t)((t + 1) * 64 + (c >> 4)) * HD +
                                       (c & 15) * 8];
          tvA[i] = *(const bf16x8*)&Vt[bhoff + (size_t)(c >> 3) * SEQ +
                                       (t + 1) * 64 + (c & 7) * 8];
        }
      }
    } else {
#pragma unroll
      for (int i = 0; i < 2; i++) {
        int c = i * 512 + tid;
        *(bf16x8*)&Ks[(c >> 4) * LDK + (c & 15) * 8] = tkA[i];
        *(bf16x8*)&Vs[(c >> 3) * LDA + (c & 7) * 8] = tvA[i];
      }
      if (t + 1 < nt) {
#pragma unroll
        for (int i = 0; i < 2; i++) {
          int c = i * 512 + tid;
          tkB[i] = *(const bf16x8*)&Kw[bhoff +
                                       (size_t)((t + 1) * 64 + (c >> 4)) * HD +
                                       (c & 15) * 8];
          tvB[i] = *(const bf16x8*)&Vt[bhoff + (size_t)(c >> 3) * SEQ +
                                       (t + 1) * 64 + (c & 7) * 8];
        }
      }
    }
    __syncthreads();  // staging visible

    const bool active = (t * 64 <= sw + 15);
    if (active) {
      floatx4 sa[4];
#pragma unroll
      for (int ni = 0; ni < 4; ni++) sa[ni] = (floatx4){0.f, 0.f, 0.f, 0.f};
      __builtin_amdgcn_s_setprio(1);
#pragma unroll
      for (int kc = 0; kc < 4; kc++) {
        bf16x8 kf[4];
#pragma unroll
        for (int ni = 0; ni < 4; ni++)
          kf[ni] =
              *(const bf16x8*)&Ks[(ni * 16 + l16) * LDK + kc * 32 + quad * 8];
#pragma unroll
        for (int ni = 0; ni < 4; ni++)
          sa[ni] = __builtin_amdgcn_mfma_f32_16x16x32_bf16(qf[kc], kf[ni],
                                                           sa[ni], 0, 0, 0);
      }
      __builtin_amdgcn_s_setprio(0);

      // online softmax, log2 domain; row = quad*4+reg, cols across 16 lanes
      float alpha[4];
#pragma unroll
      for (int reg = 0; reg < 4; reg++) {
        int sq = sw + quad * 4 + reg;
        int rr = quad * 4 + reg;
        float rv[4];
#pragma unroll
        for (int ni = 0; ni < 4; ni++) {
          int sk = t * 64 + ni * 16 + l16;
          float v = sa[ni][reg] * SCL2;
          if (sk > sq) v = MSK2;
          rv[ni] = v;
        }
        float rmax = fmaxf(fmaxf(rv[0], rv[1]), fmaxf(rv[2], rv[3]));
        rmax = fmaxf(rmax, __shfl_xor(rmax, 1));
        rmax = fmaxf(rmax, __shfl_xor(rmax, 2));
        rmax = fmaxf(rmax, __shfl_xor(rmax, 4));
        rmax = fmaxf(rmax, __shfl_xor(rmax, 8));
        float mn = fmaxf(mst[reg], rmax);
        float al = exp2f(mst[reg] - mn);
        float rs = 0.f;
#pragma unroll
        for (int ni = 0; ni < 4; ni++) {
          float p = exp2f(rv[ni] - mn);
          rs += p;
          // swizzled P store: elem = rr*64 + ((ni*16+l16) ^ ((rr&7)<<3))
          Pl[pw + rr * 64 + (((ni * 16 + l16)) ^ ((rr & 7) << 3))] = f2bf(p);
        }
        rs += __shfl_xor(rs, 1);
        rs += __shfl_xor(rs, 2);
        rs += __shfl_xor(rs, 4);
        rs += __shfl_xor(rs, 8);
        lst[reg] = lst[reg] * al + rs;
        mst[reg] = mn;
        alpha[reg] = al;
      }
#pragma unroll
      for (int ni = 0; ni < 8; ni++)
#pragma unroll
        for (int reg = 0; reg < 4; reg++) o[ni][reg] *= alpha[reg];

      // PV: P is wave-private, same-wave LDS ops complete in order -> no barrier
      __builtin_amdgcn_s_setprio(1);
#pragma unroll
      for (int kc = 0; kc < 2; kc++) {
        bf16x8 pf = *(const bf16x8*)&Pl[pw + l16 * 64 +
                                        ((kc * 32 + quad * 8) ^
                                         ((l16 & 7) << 3))];
#pragma unroll
        for (int ni = 0; ni < 8; ni++) {
          bf16x8 vf =
              *(const bf16x8*)&Vs[(ni * 16 + l16) * LDA + kc * 32 + quad * 8];
          o[ni] = __builtin_amdgcn_mfma_f32_16x16x32_bf16(pf, vf, o[ni], 0, 0,
                                                          0);
        }
      }
      __builtin_amdgcn_s_setprio(0);
    }
  }

  // final 1/l and store ctx [s][b][h*128+d]
#pragma unroll
  for (int reg = 0; reg < 4; reg++) {
    float inv = 1.0f / lst[reg];
    int sq = sw + quad * 4 + reg;
    size_t rbase = ((size_t)(sq * BATCH + b)) * HID + h * HD;
#pragma unroll
    for (int ni = 0; ni < 8; ni++)
      ctx[rbase + ni * 16 + l16] = f2bf(o[ni][reg] * inv);
  }
}

// ---------- dense GEMM (ctx bf16 @ wd bf16, gload_lds both) -> FP32 out -----
__global__ __launch_bounds__(256, 2) void dense_gemm(
    const u16* __restrict__ A, const u16* __restrict__ Wd,
    float* __restrict__ out) {
  __shared__ __align__(16) u16 As[128 * 64];
  __shared__ __align__(16) u16 Bs[128 * 64];
  const int tid = threadIdx.x;
  const int wv = tid >> 6, lane = tid & 63;
  const int quad = lane >> 4, l16 = lane & 15;
  const int bn = blockIdx.x, bm = blockIdx.y;
  const int rowA0 = bm * 128, rowB0 = bn * 128;
  const int wm = (wv >> 1) * 64;
  const int wn = (wv & 1) * 64;
  const int ntoff[4] = {wn, wn + 16, wn + 32, wn + 48};

  const int lrow = wv * 32 + (lane >> 3);
  const int lcol = (lane & 7) * 8;
  const u16* Ag = A + (size_t)(rowA0 + lrow) * HID + lcol;
  const u16* Bg = Wd + (size_t)(rowB0 + lrow) * HID + lcol;
  u16* Al = &As[(wv * 32) * 64];
  u16* Bl = &Bs[(wv * 32) * 64];

  floatx4 acc[4][4];
#pragma unroll
  for (int i = 0; i < 4; i++)
#pragma unroll
    for (int j = 0; j < 4; j++) acc[i][j] = (floatx4){0.f, 0.f, 0.f, 0.f};

  for (int kb = 0; kb < HID; kb += 64) {
#pragma unroll
    for (int j = 0; j < 4; j++) {
      gl16(Ag + (size_t)j * 8 * HID + kb, Al + j * 8 * 64);
      gl16(Bg + (size_t)j * 8 * HID + kb, Bl + j * 8 * 64);
    }
    __syncthreads();
#pragma unroll
    for (int ks = 0; ks < 64; ks += 32) {
      bf16x8 af[4], bfr[4];
#pragma unroll
      for (int mi = 0; mi < 4; mi++)
        af[mi] = *(const bf16x8*)&As[(wm + mi * 16 + l16) * 64 + ks + quad * 8];
#pragma unroll
      for (int ni = 0; ni < 4; ni++)
        bfr[ni] = *(const bf16x8*)&Bs[(ntoff[ni] + l16) * 64 + ks + quad * 8];
#pragma unroll
      for (int mi = 0; mi < 4; mi++)
#pragma unroll
        for (int ni = 0; ni < 4; ni++)
          acc[mi][ni] = __builtin_amdgcn_mfma_f32_16x16x32_bf16(
              af[mi], bfr[ni], acc[mi][ni], 0, 0, 0);
    }
    __syncthreads();
  }

#pragma unroll
  for (int mi = 0; mi < 4; mi++)
#pragma unroll
    for (int reg = 0; reg < 4; reg++) {
      int r = rowA0 + wm + mi * 16 + quad * 4 + reg;
#pragma unroll
      for (int ni = 0; ni < 4; ni++)
        out[(size_t)r * HID + bn * 128 + ntoff[ni] + l16] = acc[mi][ni][reg];
    }
}

// ---------------- bias passthrough (fp32 in -> fp32 out tail) ----------------
__global__ void copy_bias(const float* __restrict__ bd, float* __restrict__ out) {
  int i = blockIdx.x * 256 + threadIdx.x;
  if (i < HID) out[(size_t)SEQ * BATCH * HID + i] = bd[i];
}

extern "C" void kernel_launch(void* const* d_in, const int* in_sizes, int n_in,
                              void* d_out, int out_size, void* d_ws,
                              size_t ws_size, hipStream_t stream) {
  // Resolve inputs BY ELEMENT COUNT (dtype-independent):
  //   hidden 8388608, mask 4194304 (unused, precedes w_dense), w_qkv 12582912,
  //   b_qkv 6144, w_dense 4194304 (LAST match wins), b_dense 2048.
  const float *hidden = nullptr, *w_qkv = nullptr, *b_qkv = nullptr;
  const float *w_dense = nullptr, *b_dense = nullptr;
  for (int i = 0; i < n_in; i++) {
    long s = in_sizes[i];
    if (s == 8388608L) hidden = (const float*)d_in[i];
    else if (s == 12582912L) w_qkv = (const float*)d_in[i];
    else if (s == 6144L) b_qkv = (const float*)d_in[i];
    else if (s == 4194304L) w_dense = (const float*)d_in[i];  // last wins
    else if (s == 2048L) b_dense = (const float*)d_in[i];
  }
  float* out = (float*)d_out;

  // Workspace: 64 MiB, time-multiplexed (see header comment).
  char* ws = (char*)d_ws;
  u16* Qw = (u16*)(ws);                 // [ 0,16M)
  u16* Kw = (u16*)(ws + 16777216ll);    // [16,32M)
  u16* Vt = (u16*)(ws + 33554432ll);    // [32,48M) after qkv_v
  u16* wb = (u16*)(ws + 33554432ll);    // [32,48M) K/Q bf16 tiles (dead by qkv_v)
  u16* Ah = (u16*)(ws + 50331648ll);    // [48,64M) bf16 hidden (dead by attn)
  u16* ctx = (u16*)(ws + 50331648ll);   // [48,64M) after attn
  u16* wd = (u16*)(ws);                 // [0,8M) bf16 w_dense (after attn)

  cvt_inputs<<<dim3(8192), dim3(256), 0, stream>>>(w_qkv, hidden, wb, Ah);
  qkv_qk<<<dim3(32, 32), dim3(256), 0, stream>>>(Ah, wb, b_qkv, Qw, Kw);
  qkv_v<<<dim3(16, 32), dim3(256), 0, stream>>>(Ah, w_qkv, b_qkv, Vt);
  attn<<<dim3(512), dim3(512), 0, stream>>>(Qw, Kw, Vt, ctx);
  cvt_wd<<<dim3(2048), dim3(256), 0, stream>>>(w_dense, wd);
  dense_gemm<<<dim3(16, 32), dim3(256), 0, stream>>>(ctx, wd, out);
  copy_bias<<<dim3(8), dim3(256), 0, stream>>>(b_dense, out);
}

// Round 3
// 459.965 us; speedup vs baseline: 1.1986x; 1.1986x over previous
//
#include <hip/hip_runtime.h>
#include <cstdint>
#include <math.h>

// ---------------------------------------------------------------------------
// ParallelAttention (GPT-NeoX style), MI355X gfx950.
//   SEQ=2048 BATCH=2 HID=2048 NH=16 HD=128, causal mask, RoPE full head dim.
// INTERFACE (established R0-R7): fp32 inputs, fp32 output, inputs resolved by
//   element count (w_dense = LAST 4194304 match; mask unused).
// R9: GEMMs on m97 structure (bf16 pre-convert + global_load_lds w16).
// R10 FAILED: 512-thr attn + reg ping-pong prefetch -> compiler picked 64
//   VGPR and spilled (WRITE_SIZE 16->169 MB). Lesson: no reg-staged prefetch.
// R11: attn = R9 4-wave geometry (VGPR=128, no spills) with:
//   - K/V staged via global_load_lds (LINEAR LDS [64][128] / [128][64]):
//     pre-swizzled global source (16B unit u -> u^(row&7)) + same XOR on the
//     LDS read side (rule #21 involution). Bank-minimal (8-phase b128) like
//     the old padded layouts, but no staging regs / ds_writes at all.
//   - LDS 51200 B -> 3 blocks/CU; 2 barriers per tile (P is wave-private,
//     proven by R10's passing run).
//   - exp2-domain softmax, s_setprio around MFMA clusters (both R10-proven).
//   - balanced qt remap: qt = (bh<16) ? x : 15-x -> co-resident block pairs
//     (bid, bid+256) have complementary tile counts (34 const).
// MFMA 16x16x32 bf16: A/B row=lane&15, k=(lane>>4)*8+j; C/D col=lane&15,
//   row=(lane>>4)*4+reg (verified m89/m91).
// global_load_lds: LDS dest is wave-uniform base + lane*16B (m104/m108) --
//   LDS must be LINEAR, source address is per-lane (pre-swizzle there).
// ---------------------------------------------------------------------------

typedef unsigned short u16;
typedef __bf16 bf16x8 __attribute__((ext_vector_type(8)));
typedef float floatx4 __attribute__((ext_vector_type(4)));

#define SEQ 2048
#define BATCH 2
#define HID 2048
#define NH 16
#define HD 128
#define LDA 72    // padded row stride (qkv_v Bs)

__device__ __forceinline__ u16 f2bf(float f) {
  union { float f; uint32_t u; } v; v.f = f;
  uint32_t u = v.u;
  return (u16)((u + 0x7FFFu + ((u >> 16) & 1u)) >> 16);
}

// pack 8 fp32 -> 8 bf16 (RNE) and store 16B
__device__ __forceinline__ void st8_bf16(u16* dst, const float* s) {
  uint32_t pk[4];
#pragma unroll
  for (int j = 0; j < 4; j++)
    pk[j] = (uint32_t)f2bf(s[2 * j]) | ((uint32_t)f2bf(s[2 * j + 1]) << 16);
  *(uint4*)dst = make_uint4(pk[0], pk[1], pk[2], pk[3]);
}

// async global->LDS, 16B per lane; lds base must be wave-uniform
__device__ __forceinline__ void gl16(const u16* g, u16* l) {
  __builtin_amdgcn_global_load_lds(
      (const __attribute__((address_space(1))) void*)g,
      (__attribute__((address_space(3))) void*)l, 16, 0, 0);
}

// ---------------- input conversion: w_qkv K/Q tiles + hidden -> bf16 --------
// wb tile order: [K head 0..15][Q head 0..15]; src tile for K h = 3h+1, Q h = 3h.
__global__ __launch_bounds__(256) void cvt_inputs(
    const float* __restrict__ W, const float* __restrict__ Hid,
    u16* __restrict__ wb, u16* __restrict__ Ah) {
  const int blk = blockIdx.x;
  const int c0 = threadIdx.x * 8;
  const float* src;
  u16* dst;
  if (blk < 4096) {
    int dt = blk >> 7, r = blk & 127;
    int srow = (dt < 16) ? ((dt * 3 + 1) * 128 + r) : (((dt - 16) * 3) * 128 + r);
    src = W + (size_t)srow * HID;
    dst = wb + (size_t)blk * HID;
  } else {
    int r = blk - 4096;
    src = Hid + (size_t)r * HID;
    dst = Ah + (size_t)r * HID;
  }
  float t[8];
  *(floatx4*)&t[0] = *(const floatx4*)(src + c0);
  *(floatx4*)&t[4] = *(const floatx4*)(src + c0 + 4);
  st8_bf16(dst + c0, t);
}

// ---------------- w_dense fp32 -> bf16 --------------------------------------
__global__ __launch_bounds__(256) void cvt_wd(const float* __restrict__ W,
                                              u16* __restrict__ wd) {
  const int r = blockIdx.x;
  const int c0 = threadIdx.x * 8;
  float t[8];
  const float* src = W + (size_t)r * HID;
  *(floatx4*)&t[0] = *(const floatx4*)(src + c0);
  *(floatx4*)&t[4] = *(const floatx4*)(src + c0 + 4);
  st8_bf16(wd + (size_t)r * HID + c0, t);
}

// ---------------- QK projection: bf16 @ bf16, gload_lds both operands -------
__global__ __launch_bounds__(256, 2) void qkv_qk(
    const u16* __restrict__ Ah, const u16* __restrict__ wb,
    const float* __restrict__ bias, u16* __restrict__ Qw,
    u16* __restrict__ Kw) {
  __shared__ __align__(16) u16 As[128 * 64];
  __shared__ __align__(16) u16 Bs[128 * 64];
  const int tid = threadIdx.x;
  const int wv = tid >> 6, lane = tid & 63;
  const int quad = lane >> 4, l16 = lane & 15;
  const int wt = blockIdx.x;  // 0..15 = K head wt, 16..31 = Q head wt-16
  const int bm = blockIdx.y;
  const int rowA0 = bm * 128;
  const int wm = (wv >> 1) * 64;
  const int wn = (wv & 1) * 32;
  const int ntoff[4] = {wn, wn + 16, wn + 64, wn + 80};

  const int lrow = wv * 32 + (lane >> 3);
  const int lcol = (lane & 7) * 8;
  const u16* Ag = Ah + (size_t)(rowA0 + lrow) * HID + lcol;
  const u16* Bg = wb + ((size_t)wt * 128 + lrow) * HID + lcol;
  u16* Al = &As[(wv * 32) * 64];  // wave-uniform
  u16* Bl = &Bs[(wv * 32) * 64];

  floatx4 acc[4][4];
#pragma unroll
  for (int i = 0; i < 4; i++)
#pragma unroll
    for (int j = 0; j < 4; j++) acc[i][j] = (floatx4){0.f, 0.f, 0.f, 0.f};

  for (int kb = 0; kb < HID; kb += 64) {
#pragma unroll
    for (int j = 0; j < 4; j++) {
      gl16(Ag + (size_t)j * 8 * HID + kb, Al + j * 8 * 64);
      gl16(Bg + (size_t)j * 8 * HID + kb, Bl + j * 8 * 64);
    }
    __syncthreads();  // drains vmcnt(0): LDS tiles ready
#pragma unroll
    for (int ks = 0; ks < 64; ks += 32) {
      bf16x8 af[4], bfr[4];
#pragma unroll
      for (int mi = 0; mi < 4; mi++)
        af[mi] = *(const bf16x8*)&As[(wm + mi * 16 + l16) * 64 + ks + quad * 8];
#pragma unroll
      for (int ni = 0; ni < 4; ni++)
        bfr[ni] = *(const bf16x8*)&Bs[(ntoff[ni] + l16) * 64 + ks + quad * 8];
#pragma unroll
      for (int mi = 0; mi < 4; mi++)
#pragma unroll
        for (int ni = 0; ni < 4; ni++)
          acc[mi][ni] = __builtin_amdgcn_mfma_f32_16x16x32_bf16(
              af[mi], bfr[ni], acc[mi][ni], 0, 0, 0);
    }
    __syncthreads();  // all waves done reading before next gload_lds overwrite
  }

  // epilogue: bias + RoPE (inline cos/sin)
  const int seg = (wt < 16) ? 1 : 0;  // 1=K, 0=Q
  const int head = wt & 15;
  u16* dst = seg ? Kw : Qw;
  float bv[4];
#pragma unroll
  for (int ni = 0; ni < 4; ni++)
    bv[ni] = bias[(head * 3 + seg) * 128 + ntoff[ni] + l16];
  const float RC = 0.20762050593045951f;  // log2(10000)/64
  const float f0 = exp2f(-(float)(wn + l16) * RC);
  const float f1 = exp2f(-(float)(wn + 16 + l16) * RC);

#pragma unroll
  for (int mi = 0; mi < 4; mi++) {
#pragma unroll
    for (int reg = 0; reg < 4; reg++) {
      int r = rowA0 + wm + mi * 16 + quad * 4 + reg;
      int s = r >> 1, b = r & 1;
      size_t base = ((size_t)(b * NH + head) * SEQ + s) * HD;
      float sv, cv;
      sincosf((float)s * f0, &sv, &cv);
      {
        float lo = acc[mi][0][reg] + bv[0];
        float hi = acc[mi][2][reg] + bv[2];
        dst[base + wn + l16] = f2bf(lo * cv - hi * sv);
        dst[base + wn + l16 + 64] = f2bf(hi * cv + lo * sv);
      }
      sincosf((float)s * f1, &sv, &cv);
      {
        float lo = acc[mi][1][reg] + bv[1];
        float hi = acc[mi][3][reg] + bv[3];
        dst[base + wn + 16 + l16] = f2bf(lo * cv - hi * sv);
        dst[base + wn + 16 + l16 + 64] = f2bf(hi * cv + lo * sv);
      }
    }
  }
}

// ---------------- V projection: A via gload_lds, W fp32 reg-staged ----------
__global__ __launch_bounds__(256, 2) void qkv_v(
    const u16* __restrict__ Ah, const float* __restrict__ W,
    const float* __restrict__ bias, u16* __restrict__ Vt) {
  __shared__ __align__(16) u16 As[128 * 64];
  __shared__ __align__(16) u16 Bs[128 * LDA];
  const int tid = threadIdx.x;
  const int wv = tid >> 6, lane = tid & 63;
  const int quad = lane >> 4, l16 = lane & 15;
  const int head = blockIdx.x;  // 0..15
  const int bm = blockIdx.y;
  const int rowA0 = bm * 128;
  const int rowB0 = (head * 3 + 2) * 128;  // V rows of original w_qkv
  const int wm = (wv >> 1) * 64;
  const int wn = (wv & 1) * 32;
  const int ntoff[4] = {wn, wn + 16, wn + 64, wn + 80};

  const int lrow = wv * 32 + (lane >> 3);
  const int lcol = (lane & 7) * 8;
  const u16* Ag = Ah + (size_t)(rowA0 + lrow) * HID + lcol;
  u16* Al = &As[(wv * 32) * 64];

  floatx4 acc[4][4];
#pragma unroll
  for (int i = 0; i < 4; i++)
#pragma unroll
    for (int j = 0; j < 4; j++) acc[i][j] = (floatx4){0.f, 0.f, 0.f, 0.f};

  for (int kb = 0; kb < HID; kb += 64) {
    float fb[4][8];
#pragma unroll
    for (int i = 0; i < 4; i++) {
      int c = i * 256 + tid;
      int row = c >> 3, k8 = (c & 7) * 8;
      const float* sb = &W[(size_t)(rowB0 + row) * HID + kb + k8];
      *(floatx4*)&fb[i][0] = *(const floatx4*)sb;
      *(floatx4*)&fb[i][4] = *(const floatx4*)(sb + 4);
    }
    __syncthreads();  // prev iteration's MFMA reads done
#pragma unroll
    for (int j = 0; j < 4; j++)
      gl16(Ag + (size_t)j * 8 * HID + kb, Al + j * 8 * 64);
#pragma unroll
    for (int i = 0; i < 4; i++) {
      int c = i * 256 + tid;
      int row = c >> 3, k8 = (c & 7) * 8;
      st8_bf16(&Bs[row * LDA + k8], fb[i]);
    }
    __syncthreads();  // drains vmcnt(0)+lgkmcnt: As,Bs ready
#pragma unroll
    for (int ks = 0; ks < 64; ks += 32) {
      bf16x8 af[4], bfr[4];
#pragma unroll
      for (int mi = 0; mi < 4; mi++)
        af[mi] = *(const bf16x8*)&As[(wm + mi * 16 + l16) * 64 + ks + quad * 8];
#pragma unroll
      for (int ni = 0; ni < 4; ni++)
        bfr[ni] = *(const bf16x8*)&Bs[(ntoff[ni] + l16) * LDA + ks + quad * 8];
#pragma unroll
      for (int mi = 0; mi < 4; mi++)
#pragma unroll
        for (int ni = 0; ni < 4; ni++)
          acc[mi][ni] = __builtin_amdgcn_mfma_f32_16x16x32_bf16(
              af[mi], bfr[ni], acc[mi][ni], 0, 0, 0);
    }
  }
  __syncthreads();

  float bv[4];
#pragma unroll
  for (int ni = 0; ni < 4; ni++)
    bv[ni] = bias[(head * 3 + 2) * 128 + ntoff[ni] + l16];
#pragma unroll
  for (int mi = 0; mi < 4; mi++) {
#pragma unroll
    for (int ni = 0; ni < 4; ni++) {
      int d = ntoff[ni] + l16;
#pragma unroll
      for (int reg = 0; reg < 4; reg++) {
        int r = rowA0 + wm + mi * 16 + quad * 4 + reg;
        int s = r >> 1, b = r & 1;
        Vt[((size_t)(b * NH + head) * HD + d) * SEQ + s] =
            f2bf(acc[mi][ni][reg] + bv[ni]);
      }
    }
  }
}

// ---------------- flash attention: R9 geometry + gload_lds K/V staging ------
__global__ __launch_bounds__(256, 2) void attn(
    const u16* __restrict__ Qw, const u16* __restrict__ Kw,
    const u16* __restrict__ Vt, u16* __restrict__ ctx) {
  __shared__ __align__(16) u16 Ks[64 * 128];     // 16384 B, linear+XOR-swz
  __shared__ __align__(16) u16 Vs[128 * 64];     // 16384 B, linear+XOR-swz
  __shared__ __align__(16) u16 Pl[4 * 32 * 72];  // 18432 B, per-wave 32x64

  const int tid = threadIdx.x;
  const int wv = tid >> 6, lane = tid & 63;
  const int quad = lane >> 4, l16 = lane & 15;
  const int bh = blockIdx.y;
  const int b = bh >> 4, h = bh & 15;
  // balanced qt: co-resident pair (bid, bid+256) = (x,y),(x,y+16) gets
  // qt = x and 15-x -> per-pair tile count 34 = const.
  const int qt = (bh < 16) ? blockIdx.x : 15 - blockIdx.x;
  const int sw = qt * 128 + wv * 32;  // this wave's 32 q-rows
  const size_t bhoff = (size_t)bh * SEQ * HD;

  bf16x8 qf[2][4];
#pragma unroll
  for (int mi = 0; mi < 2; mi++)
#pragma unroll
    for (int kc = 0; kc < 4; kc++)
      qf[mi][kc] = *(const bf16x8*)&Qw[bhoff +
                                       (size_t)(sw + mi * 16 + l16) * HD +
                                       kc * 32 + quad * 8];

  floatx4 o[2][8];
#pragma unroll
  for (int mi = 0; mi < 2; mi++)
#pragma unroll
    for (int ni = 0; ni < 8; ni++) o[mi][ni] = (floatx4){0.f, 0.f, 0.f, 0.f};
  float mst[2][4], lst[2][4];
#pragma unroll
  for (int mi = 0; mi < 2; mi++)
#pragma unroll
    for (int r = 0; r < 4; r++) { mst[mi][r] = -1e30f; lst[mi][r] = 0.f; }

  const int nt = qt * 2 + 2;
  // log2-domain softmax (R10-proven): scale*log2e folded; mask=-10000*log2e
  const float SCL2 = 0.088388347648318447f * 1.442695040888963f;
  const float MSK2 = -10000.0f * 1.442695040888963f;

  for (int t = 0; t < nt; t++) {
    __syncthreads();  // all waves done reading Ks/Vs of prev tile
    // stage K [64][128] and V [128][64] via gload_lds; source pre-swizzled
    // by 16B unit u -> u^(row&7); read side applies the same XOR.
#pragma unroll
    for (int i = 0; i < 4; i++) {
      int c = i * 256 + tid;
      int rk = c >> 4, uk = c & 15;
      gl16(&Kw[bhoff + (size_t)(t * 64 + rk) * HD + (uk ^ (rk & 7)) * 8],
           &Ks[(i * 256 + wv * 64) * 8]);
      int rv = c >> 3, uv = c & 7;
      gl16(&Vt[bhoff + (size_t)rv * SEQ + t * 64 + (uv ^ (rv & 7)) * 8],
           &Vs[(i * 256 + wv * 64) * 8]);
    }
    __syncthreads();  // drains vmcnt(0): tiles ready

    const bool active = (t * 64 <= sw + 31);
    if (active) {
      floatx4 sa[2][4];
#pragma unroll
      for (int mi = 0; mi < 2; mi++)
#pragma unroll
        for (int ni = 0; ni < 4; ni++) sa[mi][ni] = (floatx4){0.f, 0.f, 0.f, 0.f};
      __builtin_amdgcn_s_setprio(1);
#pragma unroll
      for (int kc = 0; kc < 4; kc++) {
        bf16x8 kf[4];
#pragma unroll
        for (int ni = 0; ni < 4; ni++)
          kf[ni] = *(const bf16x8*)&Ks[(ni * 16 + l16) * 128 +
                                       (((kc * 4 + quad) ^ (l16 & 7)) * 8)];
#pragma unroll
        for (int mi = 0; mi < 2; mi++)
#pragma unroll
          for (int ni = 0; ni < 4; ni++)
            sa[mi][ni] = __builtin_amdgcn_mfma_f32_16x16x32_bf16(
                qf[mi][kc], kf[ni], sa[mi][ni], 0, 0, 0);
      }
      __builtin_amdgcn_s_setprio(0);

      // online softmax per row (row = quad*4+reg, replicated across 16 lanes)
      float alpha[2][4];
#pragma unroll
      for (int mi = 0; mi < 2; mi++) {
#pragma unroll
        for (int reg = 0; reg < 4; reg++) {
          int sq = sw + mi * 16 + quad * 4 + reg;
          float rv[4];
#pragma unroll
          for (int ni = 0; ni < 4; ni++) {
            int sk = t * 64 + ni * 16 + l16;
            float v = sa[mi][ni][reg] * SCL2;
            if (sk > sq) v = MSK2;
            rv[ni] = v;
          }
          float rmax = fmaxf(fmaxf(rv[0], rv[1]), fmaxf(rv[2], rv[3]));
          rmax = fmaxf(rmax, __shfl_xor(rmax, 1));
          rmax = fmaxf(rmax, __shfl_xor(rmax, 2));
          rmax = fmaxf(rmax, __shfl_xor(rmax, 4));
          rmax = fmaxf(rmax, __shfl_xor(rmax, 8));
          float mn = fmaxf(mst[mi][reg], rmax);
          float al = exp2f(mst[mi][reg] - mn);
          float rs = 0.f;
#pragma unroll
          for (int ni = 0; ni < 4; ni++) {
            float p = exp2f(rv[ni] - mn);
            rs += p;
            Pl[wv * 2304 + (mi * 16 + quad * 4 + reg) * 72 + ni * 16 + l16] =
                f2bf(p);
          }
          rs += __shfl_xor(rs, 1);
          rs += __shfl_xor(rs, 2);
          rs += __shfl_xor(rs, 4);
          rs += __shfl_xor(rs, 8);
          lst[mi][reg] = lst[mi][reg] * al + rs;
          mst[mi][reg] = mn;
          alpha[mi][reg] = al;
        }
      }
#pragma unroll
      for (int mi = 0; mi < 2; mi++)
#pragma unroll
        for (int ni = 0; ni < 8; ni++)
#pragma unroll
          for (int reg = 0; reg < 4; reg++)
            o[mi][ni][reg] *= alpha[mi][reg];

      // PV: P is wave-private (same-wave ds ordering, R10-proven) -> no barrier
      __builtin_amdgcn_s_setprio(1);
#pragma unroll
      for (int kc = 0; kc < 2; kc++) {
        bf16x8 pf[2];
#pragma unroll
        for (int mi = 0; mi < 2; mi++)
          pf[mi] = *(const bf16x8*)&Pl[wv * 2304 + (mi * 16 + l16) * 72 +
                                       kc * 32 + quad * 8];
#pragma unroll
        for (int ni = 0; ni < 8; ni++) {
          bf16x8 vf = *(const bf16x8*)&Vs[(ni * 16 + l16) * 64 +
                                          (((kc * 4 + quad) ^ (l16 & 7)) * 8)];
#pragma unroll
          for (int mi = 0; mi < 2; mi++)
            o[mi][ni] = __builtin_amdgcn_mfma_f32_16x16x32_bf16(
                pf[mi], vf, o[mi][ni], 0, 0, 0);
        }
      }
      __builtin_amdgcn_s_setprio(0);
    }
  }

  // final 1/l and store ctx [s][b][h*128+d]
#pragma unroll
  for (int mi = 0; mi < 2; mi++) {
#pragma unroll
    for (int reg = 0; reg < 4; reg++) {
      float inv = 1.0f / lst[mi][reg];
      int sq = sw + mi * 16 + quad * 4 + reg;
      size_t rbase = ((size_t)(sq * BATCH + b)) * HID + h * HD;
#pragma unroll
      for (int ni = 0; ni < 8; ni++)
        ctx[rbase + ni * 16 + l16] = f2bf(o[mi][ni][reg] * inv);
    }
  }
}

// ---------- dense GEMM (ctx bf16 @ wd bf16, gload_lds both) -> FP32 out -----
__global__ __launch_bounds__(256, 2) void dense_gemm(
    const u16* __restrict__ A, const u16* __restrict__ Wd,
    float* __restrict__ out) {
  __shared__ __align__(16) u16 As[128 * 64];
  __shared__ __align__(16) u16 Bs[128 * 64];
  const int tid = threadIdx.x;
  const int wv = tid >> 6, lane = tid & 63;
  const int quad = lane >> 4, l16 = lane & 15;
  const int bn = blockIdx.x, bm = blockIdx.y;
  const int rowA0 = bm * 128, rowB0 = bn * 128;
  const int wm = (wv >> 1) * 64;
  const int wn = (wv & 1) * 64;
  const int ntoff[4] = {wn, wn + 16, wn + 32, wn + 48};

  const int lrow = wv * 32 + (lane >> 3);
  const int lcol = (lane & 7) * 8;
  const u16* Ag = A + (size_t)(rowA0 + lrow) * HID + lcol;
  const u16* Bg = Wd + (size_t)(rowB0 + lrow) * HID + lcol;
  u16* Al = &As[(wv * 32) * 64];
  u16* Bl = &Bs[(wv * 32) * 64];

  floatx4 acc[4][4];
#pragma unroll
  for (int i = 0; i < 4; i++)
#pragma unroll
    for (int j = 0; j < 4; j++) acc[i][j] = (floatx4){0.f, 0.f, 0.f, 0.f};

  for (int kb = 0; kb < HID; kb += 64) {
#pragma unroll
    for (int j = 0; j < 4; j++) {
      gl16(Ag + (size_t)j * 8 * HID + kb, Al + j * 8 * 64);
      gl16(Bg + (size_t)j * 8 * HID + kb, Bl + j * 8 * 64);
    }
    __syncthreads();
#pragma unroll
    for (int ks = 0; ks < 64; ks += 32) {
      bf16x8 af[4], bfr[4];
#pragma unroll
      for (int mi = 0; mi < 4; mi++)
        af[mi] = *(const bf16x8*)&As[(wm + mi * 16 + l16) * 64 + ks + quad * 8];
#pragma unroll
      for (int ni = 0; ni < 4; ni++)
        bfr[ni] = *(const bf16x8*)&Bs[(ntoff[ni] + l16) * 64 + ks + quad * 8];
#pragma unroll
      for (int mi = 0; mi < 4; mi++)
#pragma unroll
        for (int ni = 0; ni < 4; ni++)
          acc[mi][ni] = __builtin_amdgcn_mfma_f32_16x16x32_bf16(
              af[mi], bfr[ni], acc[mi][ni], 0, 0, 0);
    }
    __syncthreads();
  }

#pragma unroll
  for (int mi = 0; mi < 4; mi++)
#pragma unroll
    for (int reg = 0; reg < 4; reg++) {
      int r = rowA0 + wm + mi * 16 + quad * 4 + reg;
#pragma unroll
      for (int ni = 0; ni < 4; ni++)
        out[(size_t)r * HID + bn * 128 + ntoff[ni] + l16] = acc[mi][ni][reg];
    }
}

// ---------------- bias passthrough (fp32 in -> fp32 out tail) ----------------
__global__ void copy_bias(const float* __restrict__ bd, float* __restrict__ out) {
  int i = blockIdx.x * 256 + threadIdx.x;
  if (i < HID) out[(size_t)SEQ * BATCH * HID + i] = bd[i];
}

extern "C" void kernel_launch(void* const* d_in, const int* in_sizes, int n_in,
                              void* d_out, int out_size, void* d_ws,
                              size_t ws_size, hipStream_t stream) {
  // Resolve inputs BY ELEMENT COUNT (dtype-independent):
  //   hidden 8388608, mask 4194304 (unused, precedes w_dense), w_qkv 12582912,
  //   b_qkv 6144, w_dense 4194304 (LAST match wins), b_dense 2048.
  const float *hidden = nullptr, *w_qkv = nullptr, *b_qkv = nullptr;
  const float *w_dense = nullptr, *b_dense = nullptr;
  for (int i = 0; i < n_in; i++) {
    long s = in_sizes[i];
    if (s == 8388608L) hidden = (const float*)d_in[i];
    else if (s == 12582912L) w_qkv = (const float*)d_in[i];
    else if (s == 6144L) b_qkv = (const float*)d_in[i];
    else if (s == 4194304L) w_dense = (const float*)d_in[i];  // last wins
    else if (s == 2048L) b_dense = (const float*)d_in[i];
  }
  float* out = (float*)d_out;

  // Workspace: 64 MiB, time-multiplexed (see header comment).
  char* ws = (char*)d_ws;
  u16* Qw = (u16*)(ws);                 // [ 0,16M)
  u16* Kw = (u16*)(ws + 16777216ll);    // [16,32M)
  u16* Vt = (u16*)(ws + 33554432ll);    // [32,48M) after qkv_v
  u16* wb = (u16*)(ws + 33554432ll);    // [32,48M) K/Q bf16 tiles (dead by qkv_v)
  u16* Ah = (u16*)(ws + 50331648ll);    // [48,64M) bf16 hidden (dead by attn)
  u16* ctx = (u16*)(ws + 50331648ll);   // [48,64M) after attn
  u16* wd = (u16*)(ws);                 // [0,8M) bf16 w_dense (after attn)

  cvt_inputs<<<dim3(8192), dim3(256), 0, stream>>>(w_qkv, hidden, wb, Ah);
  qkv_qk<<<dim3(32, 32), dim3(256), 0, stream>>>(Ah, wb, b_qkv, Qw, Kw);
  qkv_v<<<dim3(16, 32), dim3(256), 0, stream>>>(Ah, w_qkv, b_qkv, Vt);
  attn<<<dim3(16, 32), dim3(256), 0, stream>>>(Qw, Kw, Vt, ctx);
  cvt_wd<<<dim3(2048), dim3(256), 0, stream>>>(w_dense, wd);
  dense_gemm<<<dim3(16, 32), dim3(256), 0, stream>>>(ctx, wd, out);
  copy_bias<<<dim3(8), dim3(256), 0, stream>>>(b_dense, out);
}